// Round 1
// baseline (4252.530 us; speedup 1.0000x reference)
//
#include <hip/hip_runtime.h>
#include <hip/hip_bf16.h>

typedef short bf16x8 __attribute__((ext_vector_type(8)));
typedef float f32x4 __attribute__((ext_vector_type(4)));

#define O_    5766
#define OP_   5792   // 181*32
#define L_    3969   // 63*63
#define LP_   4000   // 125*32
#define K2_   23814  // 3969*6
#define K2P_  23840  // 745*32
#define NB_   768    // 3*256
#define NM_   256
#define NA_   4608   // 18*256
#define S_    504

enum { EPI_F32 = 0, EPI_ATOM = 1, EPI_BKG = 2, EPI_AUX = 3 };

// ---------------- materialization kernels ----------------

// cos [O_][L_] f32  ->  cosT [4096 rows alloc][OP_] bf16 (cols >= O_ zeroed)
__global__ __launch_bounds__(256) void k_cos_transpose(const float* __restrict__ src,
                                                       __hip_bfloat16* __restrict__ dst) {
  __shared__ __hip_bfloat16 tile[64][65];
  int o0 = blockIdx.x * 64;
  int j0 = blockIdx.y * 64;
  int tx = threadIdx.x & 63;
  int ty = threadIdx.x >> 6;
#pragma unroll
  for (int r = ty; r < 64; r += 4) {
    int o = o0 + r, ij = j0 + tx;
    float v = 0.f;
    if (o < O_ && ij < L_) v = src[(size_t)o * L_ + ij];
    tile[r][tx] = __float2bfloat16(v);
  }
  __syncthreads();
#pragma unroll
  for (int r = ty; r < 64; r += 4) {
    int ij = j0 + r, o = o0 + tx;
    if (ij < L_ && o < OP_) dst[(size_t)ij * OP_ + o] = tile[tx][r];
  }
}

// replicate-pad unfold, transposed: dst[(d*256+ph*16+pw)][li*63+lj] ; cols >= L_ zero
__global__ __launch_bounds__(256) void k_patch(const float* __restrict__ src,
                                               __hip_bfloat16* __restrict__ dst, int C) {
  int idx = blockIdx.x * 256 + threadIdx.x;
  int total = C * 256 * LP_;
  if (idx >= total) return;
  int row = idx / LP_, col = idx - row * LP_;
  float v = 0.f;
  if (col < L_) {
    int d = row >> 8, hw = row & 255;
    int ph = hw >> 4, pw = hw & 15;
    int li = col / 63, lj = col - li * 63;
    int y = 8 * li + ph - 4; y = y < 0 ? 0 : (y > 503 ? 503 : y);
    int x = 8 * lj + pw - 4; x = x < 0 ? 0 : (x > 503 ? 503 : x);
    v = src[((size_t)d * S_ + y) * S_ + x];
  }
  dst[idx] = __float2bfloat16(v);
}

// mask patches: dst[hw][l*6 + c] (K2 layout), cols >= K2_ zero
__global__ __launch_bounds__(256) void k_patch_m(const float* __restrict__ src,
                                                 __hip_bfloat16* __restrict__ dst) {
  int idx = blockIdx.x * 256 + threadIdx.x;
  if (idx >= NM_ * K2P_) return;
  int row = idx / K2P_, col = idx - row * K2P_;
  float v = 0.f;
  if (col < K2_) {
    int l = col / 6, c = col - l * 6;
    int ph = row >> 4, pw = row & 15;
    int li = l / 63, lj = l - li * 63;
    int y = 8 * li + ph - 4; y = y < 0 ? 0 : (y > 503 ? 503 : y);
    int x = 8 * lj + pw - 4; x = x < 0 ? 0 : (x > 503 ? 503 : x);
    v = src[((size_t)c * S_ + y) * S_ + x];
  }
  dst[idx] = __float2bfloat16(v);
}

// f32 [rows][cin] -> bf16 [rows][cout], cols >= cin zeroed
__global__ __launch_bounds__(256) void k_cvt_pad(const float* __restrict__ src,
                                                 __hip_bfloat16* __restrict__ dst,
                                                 int rows, int cin, int cout) {
  int idx = blockIdx.x * 256 + threadIdx.x;
  if (idx >= rows * cout) return;
  int r = idx / cout, c = idx - r * cout;
  float v = (c < cin) ? src[(size_t)r * cin + c] : 0.f;
  dst[idx] = __float2bfloat16(v);
}

// first-max argmax over o of cos[o][ij]  (exact f32, matches jnp.argmax)
__global__ __launch_bounds__(256) void k_argmax(const float* __restrict__ cos_,
                                                int* __restrict__ ostar) {
  __shared__ float sval[4][64];
  __shared__ int sidx[4][64];
  int lanej = threadIdx.x & 63;
  int ty = threadIdx.x >> 6;
  int ij = blockIdx.x * 64 + lanej;
  float best = -1.f; int bi = 0;
  if (ij < L_) {
    for (int o = ty; o < O_; o += 4) {
      float v = cos_[(size_t)o * L_ + ij];
      if (v > best) { best = v; bi = o; }
    }
  }
  sval[ty][lanej] = best; sidx[ty][lanej] = bi;
  __syncthreads();
  if (ty == 0 && ij < L_) {
#pragma unroll
    for (int t = 1; t < 4; ++t) {
      float v = sval[t][lanej]; int i2 = sidx[t][lanej];
      if (v > best || (v == best && i2 < bi)) { best = v; bi = i2; }
    }
    ostar[ij] = bi;
  }
}

// ---------------- GEMM:  C[m,n] = sum_k A[m,k] * BT[n,k] ----------------

template<bool F32>
__device__ __forceinline__ void stage_tile(const void* __restrict__ src,
                                           __hip_bfloat16* dst,
                                           int r0, int k0, int Rreal, int Kreal,
                                           int ld, int tid) {
  const int srow = tid >> 1;
  const int scol = (tid & 1) << 4;
  if (!F32) {
    const __hip_bfloat16* g = (const __hip_bfloat16*)src + (size_t)(r0 + srow) * ld + k0 + scol;
    uint4 v0 = *(const uint4*)(g);
    uint4 v1 = *(const uint4*)(g + 8);
    *(uint4*)(dst + srow * 32 + scol) = v0;
    *(uint4*)(dst + srow * 32 + scol + 8) = v1;
  } else {
    const float* g = (const float*)src + (size_t)(r0 + srow) * ld + k0 + scol;
    const bool rok = (r0 + srow) < Rreal;
    alignas(16) __hip_bfloat16 tmp[16];
#pragma unroll
    for (int c = 0; c < 16; ++c) {
      float v = 0.f;
      if (rok && (k0 + scol + c) < Kreal) v = g[c];
      tmp[c] = __float2bfloat16(v);
    }
    *(uint4*)(dst + srow * 32 + scol) = *(const uint4*)(tmp);
    *(uint4*)(dst + srow * 32 + scol + 8) = *(const uint4*)(tmp + 8);
  }
}

template<int EPI, bool AF32, bool BF32>
__global__ __launch_bounds__(256) void k_gemm(
    const void* __restrict__ Ap, const void* __restrict__ Bp,
    float* __restrict__ Cf, __hip_bfloat16* __restrict__ Cb,
    const float* __restrict__ bias, const float* __restrict__ mskf,
    int M, int N, int Kreal, int lda, int ldb, int ldc, int Npad,
    int ktPerSlice, int KT)
{
  __shared__ __attribute__((aligned(16))) __hip_bfloat16 As[128 * 32];
  __shared__ __attribute__((aligned(16))) __hip_bfloat16 Bs[128 * 32];
  const int tid = threadIdx.x;
  const int lane = tid & 63;
  const int wave = tid >> 6;
  const int wm = wave >> 1, wn = wave & 1;
  const int m0 = blockIdx.y * 128, n0 = blockIdx.x * 128;
  int kt0 = blockIdx.z * ktPerSlice;
  int kt1 = kt0 + ktPerSlice; if (kt1 > KT) kt1 = KT;

  f32x4 acc[4][4];
  f32x4 zero = {0.f, 0.f, 0.f, 0.f};
#pragma unroll
  for (int i = 0; i < 4; ++i)
#pragma unroll
    for (int j = 0; j < 4; ++j) acc[i][j] = zero;

  for (int kt = kt0; kt < kt1; ++kt) {
    const int k0 = kt * 32;
    stage_tile<AF32>(Ap, As, m0, k0, M, Kreal, lda, tid);
    stage_tile<BF32>(Bp, Bs, n0, k0, N, Kreal, ldb, tid);
    __syncthreads();
    bf16x8 af[4], bfv[4];
#pragma unroll
    for (int mi = 0; mi < 4; ++mi)
      af[mi] = *(const bf16x8*)(As + (wm * 64 + mi * 16 + (lane & 15)) * 32 + (lane >> 4) * 8);
#pragma unroll
    for (int ni = 0; ni < 4; ++ni)
      bfv[ni] = *(const bf16x8*)(Bs + (wn * 64 + ni * 16 + (lane & 15)) * 32 + (lane >> 4) * 8);
#pragma unroll
    for (int mi = 0; mi < 4; ++mi)
#pragma unroll
      for (int ni = 0; ni < 4; ++ni)
        acc[mi][ni] = __builtin_amdgcn_mfma_f32_16x16x32_bf16(af[mi], bfv[ni], acc[mi][ni], 0, 0, 0);
    __syncthreads();
  }

  const int rb = (lane >> 4) * 4;
  const int cb = lane & 15;
#pragma unroll
  for (int mi = 0; mi < 4; ++mi) {
#pragma unroll
    for (int ni = 0; ni < 4; ++ni) {
      const int col = n0 + wn * 64 + ni * 16 + cb;
#pragma unroll
      for (int r = 0; r < 4; ++r) {
        const int row = m0 + wm * 64 + mi * 16 + rb + r;
        const float v = acc[mi][ni][r];
        if (EPI == EPI_F32) {
          if (row < M && col < N) Cf[(size_t)row * ldc + col] = v;
        } else if (EPI == EPI_ATOM) {
          if (row < M && col < N) atomicAdd(Cf + (size_t)row * ldc + col, v);
        } else if (EPI == EPI_BKG) {
          if (row < M && col < Npad) {
            float ov = 0.f;
            if (col < N) ov = (v + bias[col]) * (1.f - mskf[(size_t)(row & 255) * ldc + col]);
            Cb[(size_t)row * ldc + col] = __float2bfloat16(ov);
          }
        } else { // EPI_AUX
          if (row < M && col < N) Cb[(size_t)row * ldc + col] = __float2bfloat16(v + bias[row]);
        }
      }
    }
  }
}

// mskF raw sums -> + bias, rewrite f32 and bf16 (pad cols -> 0)
__global__ __launch_bounds__(256) void k_msk_fin(float* __restrict__ mskF,
                                                 __hip_bfloat16* __restrict__ mskB,
                                                 const float* __restrict__ b2) {
  int idx = blockIdx.x * 256 + threadIdx.x;
  if (idx >= NM_ * OP_) return;
  int n = idx % OP_;
  float v = 0.f;
  if (n < O_) v = mskF[idx] + b2[n];
  mskF[idx] = v;
  mskB[idx] = __float2bfloat16(v);
}

// ---------------- patch overlap-add / epilogue kernels ----------------

__device__ __forceinline__ int cntv(int t) { return (t >= 8 && t < 504) ? 2 : 1; }

__global__ __launch_bounds__(256) void k_out_asm(const float* __restrict__ P, float* __restrict__ out) {
  int idx = blockIdx.x * 256 + threadIdx.x;
  if (idx >= 3 * S_ * S_) return;
  int x = idx % S_;
  int t = idx / S_;
  int y = t % S_;
  int d = t / S_;
  int Y = y + 4, X = x + 4;
  int iy0 = (Y - 8) >> 3; if (iy0 < 0) iy0 = 0;
  int iy1 = Y >> 3; if (iy1 > 62) iy1 = 62;
  int jx0 = (X - 8) >> 3; if (jx0 < 0) jx0 = 0;
  int jx1 = X >> 3; if (jx1 > 62) jx1 = 62;
  float s = 0.f;
  for (int i = iy0; i <= iy1; ++i)
    for (int j = jx0; j <= jx1; ++j)
      s += P[(size_t)(i * 63 + j) * NB_ + d * 256 + (Y - 8 * i) * 16 + (X - 8 * j)];
  out[idx] = s;
}

__global__ __launch_bounds__(256) void k_mr512(const float* __restrict__ P, float* __restrict__ mr) {
  int idx = blockIdx.x * 256 + threadIdx.x;
  if (idx >= 512 * 512) return;
  int x = idx & 511, y = idx >> 9;
  int iy0 = (y - 8) >> 3; if (iy0 < 0) iy0 = 0;
  int iy1 = y >> 3; if (iy1 > 62) iy1 = 62;
  int jx0 = (x - 8) >> 3; if (jx0 < 0) jx0 = 0;
  int jx1 = x >> 3; if (jx1 > 62) jx1 = 62;
  float s = 0.f;
  for (int i = iy0; i <= iy1; ++i)
    for (int j = jx0; j <= jx1; ++j)
      s += P[(size_t)(i * 63 + j) * NM_ + (y - 8 * i) * 16 + (x - 8 * j)];
  mr[idx] = s;
}

__global__ __launch_bounds__(256) void k_hole(const float* __restrict__ mr,
                                              const float* __restrict__ up2w, const float* __restrict__ up2b,
                                              const float* __restrict__ up3w, const float* __restrict__ up3b,
                                              float* __restrict__ out) {
  int idx = blockIdx.x * 256 + threadIdx.x;
  if (idx >= 6 * 1016 * 1016) return;
  int X = idx % 1016;
  int t = idx / 1016;
  int Y = t % 1016;
  int c = t / 1016;
  int Yp = Y + 4, Xp = X + 4;
  int ys = Yp >> 1, xs = Xp >> 1;
  int ky = Yp & 1, kx = Xp & 1;
  float mv = mr[ys * 512 + xs] * up2w[(c << 2) | (ky << 1) | kx] + up2b[c];
  float wmv = (float)(cntv(ys) * cntv(xs)) * up3w[(ky << 1) | kx] + up3b[0];
  out[idx] = mv / wmv;
}

__global__ __launch_bounds__(256) void k_raw(const __hip_bfloat16* __restrict__ aux,
                                             const int* __restrict__ ostar,
                                             float* __restrict__ out) {
  int idx = blockIdx.x * 256 + threadIdx.x;
  if (idx >= 18 * S_ * S_) return;
  int x = idx % S_;
  int t = idx / S_;
  int y = t % S_;
  int d = t / S_;
  int Y = y + 4, X = x + 4;
  int iy0 = (Y - 8) >> 3; if (iy0 < 0) iy0 = 0;
  int iy1 = Y >> 3; if (iy1 > 62) iy1 = 62;
  int jx0 = (X - 8) >> 3; if (jx0 < 0) jx0 = 0;
  int jx1 = X >> 3; if (jx1 > 62) jx1 = 62;
  float s = 0.f;
  for (int i = iy0; i <= iy1; ++i)
    for (int j = jx0; j <= jx1; ++j) {
      int o = ostar[i * 63 + j];
      s += __bfloat162float(aux[(size_t)o * NA_ + d * 256 + (Y - 8 * i) * 16 + (X - 8 * j)]);
    }
  s /= (float)(cntv(Y) * cntv(X));
  out[idx] = s;
}

// ---------------- launch ----------------

extern "C" void kernel_launch(void* const* d_in, const int* in_sizes, int n_in,
                              void* d_out, int out_size, void* d_ws, size_t ws_size,
                              hipStream_t stream) {
  const float* cos_  = (const float*)d_in[0];
  const float* bimg  = (const float*)d_in[1];
  const float* mask  = (const float*)d_in[2];
  const float* auxr  = (const float*)d_in[3];
  const float* w1    = (const float*)d_in[4];
  const float* b1    = (const float*)d_in[5];
  const float* w2    = (const float*)d_in[6];
  const float* b2    = (const float*)d_in[7];
  const float* waux  = (const float*)d_in[8];
  const float* baux  = (const float*)d_in[9];
  const float* up2w  = (const float*)d_in[10];
  const float* up2b  = (const float*)d_in[11];
  const float* up3w  = (const float*)d_in[12];
  const float* up3b  = (const float*)d_in[13];
  (void)in_sizes; (void)n_in; (void)out_size; (void)ws_size;

  char* ws = (char*)d_ws;
  size_t off = 0;
  auto take = [&](size_t bytes) { char* p = ws + off; off += (bytes + 255) & ~(size_t)255; return p; };
  __hip_bfloat16* cosT  = (__hip_bfloat16*)take((size_t)4096 * OP_ * 2);   // [4096][OP_]
  __hip_bfloat16* bP    = (__hip_bfloat16*)take((size_t)NB_ * LP_ * 2);    // [768][4000]
  __hip_bfloat16* mP    = (__hip_bfloat16*)take((size_t)NM_ * K2P_ * 2);   // [256][23840]
  __hip_bfloat16* aP    = (__hip_bfloat16*)take((size_t)NA_ * LP_ * 2);    // [4608][4000]
  __hip_bfloat16* wXb   = (__hip_bfloat16*)take((size_t)5888 * LP_ * 2);   // waux bf16, M-padded
  float*          mskF  = (float*)take((size_t)NM_ * OP_ * 4);             // [256][OP_] f32
  __hip_bfloat16* mskB  = (__hip_bfloat16*)take((size_t)NM_ * OP_ * 2);
  __hip_bfloat16* bkgB  = (__hip_bfloat16*)take((size_t)NB_ * OP_ * 2);
  __hip_bfloat16* auxB  = (__hip_bfloat16*)take((size_t)O_ * NA_ * 2);     // [5766][4608]
  float*          Pout  = (float*)take((size_t)L_ * NB_ * 4);
  float*          Pmsk  = (float*)take((size_t)L_ * NM_ * 4);
  int*            ostar = (int*)take((size_t)L_ * 4);
  float*          mr    = (float*)take((size_t)512 * 512 * 4);

  float* outMain = (float*)d_out;            // [3][504][504]
  float* outHole = outMain + 762048;         // [6][1016][1016]
  float* outRaw  = outMain + 6955584;        // [18][504][504]

  // materialize bf16 operands
  k_cos_transpose<<<dim3(91, 63), 256, 0, stream>>>(cos_, cosT);
  k_patch<<<(NB_ * LP_ + 255) / 256, 256, 0, stream>>>(bimg, bP, 3);
  k_patch<<<(NA_ * LP_ + 255) / 256, 256, 0, stream>>>(auxr, aP, 18);
  k_patch_m<<<(NM_ * K2P_ + 255) / 256, 256, 0, stream>>>(mask, mP);
  k_cvt_pad<<<(O_ * LP_ + 255) / 256, 256, 0, stream>>>(waux, wXb, O_, L_, LP_);
  k_argmax<<<63, 256, 0, stream>>>(cos_, ostar);

  // GEMM B: mskT[hw][o]  (split-K=8, atomic)
  hipMemsetAsync(mskF, 0, (size_t)NM_ * OP_ * 4, stream);
  k_gemm<EPI_ATOM, false, true><<<dim3(46, 2, 8), 256, 0, stream>>>(
      mP, w2, mskF, nullptr, nullptr, nullptr,
      NM_, O_, K2_, K2P_, K2_, OP_, OP_, 94, 745);
  k_msk_fin<<<(NM_ * OP_ + 255) / 256, 256, 0, stream>>>(mskF, mskB, b2);

  // GEMM A: bkgT[dhw][o] = (sum + b1) * (1 - msk)
  k_gemm<EPI_BKG, false, true><<<dim3(46, 6, 1), 256, 0, stream>>>(
      bP, w1, nullptr, bkgB, b1, mskF,
      NB_, O_, L_, LP_, L_, OP_, OP_, 125, 125);

  // GEMM C: aux[o][dhw] = sum + baux[o]
  k_gemm<EPI_AUX, false, false><<<dim3(36, 46, 1), 256, 0, stream>>>(
      wXb, aP, nullptr, auxB, baux, nullptr,
      O_, NA_, L_, LP_, LP_, NA_, NA_, 125, 125);

  // GEMM D: P_out[ij][dhw]
  k_gemm<EPI_F32, false, false><<<dim3(6, 32, 1), 256, 0, stream>>>(
      cosT, bkgB, Pout, nullptr, nullptr, nullptr,
      L_, NB_, OP_, OP_, OP_, NB_, NB_, 181, 181);

  // GEMM E: P_msk[ij][hw]  (split-K=4, atomic)
  hipMemsetAsync(Pmsk, 0, (size_t)L_ * NM_ * 4, stream);
  k_gemm<EPI_ATOM, false, false><<<dim3(2, 32, 4), 256, 0, stream>>>(
      cosT, mskB, Pmsk, nullptr, nullptr, nullptr,
      L_, NM_, OP_, OP_, OP_, NM_, NM_, 46, 181);

  // assemble outputs
  k_out_asm<<<(3 * S_ * S_ + 255) / 256, 256, 0, stream>>>(Pout, outMain);
  k_mr512<<<(512 * 512) / 256, 256, 0, stream>>>(Pmsk, mr);
  k_hole<<<(6 * 1016 * 1016 + 255) / 256, 256, 0, stream>>>(mr, up2w, up2b, up3w, up3b, outHole);
  k_raw<<<(18 * S_ * S_ + 255) / 256, 256, 0, stream>>>(auxB, ostar, outRaw);
}

// Round 2
// 2705.082 us; speedup vs baseline: 1.5721x; 1.5721x over previous
//
#include <hip/hip_runtime.h>
#include <hip/hip_bf16.h>

typedef short bf16x8 __attribute__((ext_vector_type(8)));
typedef float f32x4 __attribute__((ext_vector_type(4)));

#define O_    5766
#define OP_   5792   // 181*32
#define L_    3969   // 63*63
#define LP_   4000   // 125*32
#define K2_   23814  // 3969*6
#define K2P_  23840  // 745*32
#define NB_   768    // 3*256
#define NM_   256
#define NA_   4608   // 18*256
#define S_    504

enum { EPI_F32 = 0, EPI_ATOM = 1, EPI_BKG = 2, EPI_AUX = 3 };

// ---------------- materialization kernels ----------------

// cos [O_][L_] f32  ->  cosT [4096 rows alloc][OP_] bf16 (cols >= O_ zeroed)
__global__ __launch_bounds__(256) void k_cos_transpose(const float* __restrict__ src,
                                                       __hip_bfloat16* __restrict__ dst) {
  __shared__ __hip_bfloat16 tile[64][65];
  int o0 = blockIdx.x * 64;
  int j0 = blockIdx.y * 64;
  int tx = threadIdx.x & 63;
  int ty = threadIdx.x >> 6;
#pragma unroll
  for (int r = ty; r < 64; r += 4) {
    int o = o0 + r, ij = j0 + tx;
    float v = 0.f;
    if (o < O_ && ij < L_) v = src[(size_t)o * L_ + ij];
    tile[r][tx] = __float2bfloat16(v);
  }
  __syncthreads();
#pragma unroll
  for (int r = ty; r < 64; r += 4) {
    int ij = j0 + r, o = o0 + tx;
    if (ij < L_ && o < OP_) dst[(size_t)ij * OP_ + o] = tile[tx][r];
  }
}

// replicate-pad unfold, transposed: dst[(d*256+ph*16+pw)][li*63+lj] ; cols >= L_ zero
__global__ __launch_bounds__(256) void k_patch(const float* __restrict__ src,
                                               __hip_bfloat16* __restrict__ dst, int C) {
  int idx = blockIdx.x * 256 + threadIdx.x;
  int total = C * 256 * LP_;
  if (idx >= total) return;
  int row = idx / LP_, col = idx - row * LP_;
  float v = 0.f;
  if (col < L_) {
    int d = row >> 8, hw = row & 255;
    int ph = hw >> 4, pw = hw & 15;
    int li = col / 63, lj = col - li * 63;
    int y = 8 * li + ph - 4; y = y < 0 ? 0 : (y > 503 ? 503 : y);
    int x = 8 * lj + pw - 4; x = x < 0 ? 0 : (x > 503 ? 503 : x);
    v = src[((size_t)d * S_ + y) * S_ + x];
  }
  dst[idx] = __float2bfloat16(v);
}

// mask patches: dst[hw][l*6 + c] (K2 layout), cols >= K2_ zero
__global__ __launch_bounds__(256) void k_patch_m(const float* __restrict__ src,
                                                 __hip_bfloat16* __restrict__ dst) {
  int idx = blockIdx.x * 256 + threadIdx.x;
  if (idx >= NM_ * K2P_) return;
  int row = idx / K2P_, col = idx - row * K2P_;
  float v = 0.f;
  if (col < K2_) {
    int l = col / 6, c = col - l * 6;
    int ph = row >> 4, pw = row & 15;
    int li = l / 63, lj = l - li * 63;
    int y = 8 * li + ph - 4; y = y < 0 ? 0 : (y > 503 ? 503 : y);
    int x = 8 * lj + pw - 4; x = x < 0 ? 0 : (x > 503 ? 503 : x);
    v = src[((size_t)c * S_ + y) * S_ + x];
  }
  dst[idx] = __float2bfloat16(v);
}

// f32 [rows][cin] -> bf16 [rows][cout], cols >= cin zeroed
__global__ __launch_bounds__(256) void k_cvt_pad(const float* __restrict__ src,
                                                 __hip_bfloat16* __restrict__ dst,
                                                 int rows, int cin, int cout) {
  int idx = blockIdx.x * 256 + threadIdx.x;
  if (idx >= rows * cout) return;
  int r = idx / cout, c = idx - r * cout;
  float v = (c < cin) ? src[(size_t)r * cin + c] : 0.f;
  dst[idx] = __float2bfloat16(v);
}

// first-max argmax over o of cos[o][ij]  (exact f32, matches jnp.argmax)
__global__ __launch_bounds__(256) void k_argmax(const float* __restrict__ cos_,
                                                int* __restrict__ ostar) {
  __shared__ float sval[4][64];
  __shared__ int sidx[4][64];
  int lanej = threadIdx.x & 63;
  int ty = threadIdx.x >> 6;
  int ij = blockIdx.x * 64 + lanej;
  float best = -1.f; int bi = 0;
  if (ij < L_) {
    for (int o = ty; o < O_; o += 4) {
      float v = cos_[(size_t)o * L_ + ij];
      if (v > best) { best = v; bi = o; }
    }
  }
  sval[ty][lanej] = best; sidx[ty][lanej] = bi;
  __syncthreads();
  if (ty == 0 && ij < L_) {
#pragma unroll
    for (int t = 1; t < 4; ++t) {
      float v = sval[t][lanej]; int i2 = sidx[t][lanej];
      if (v > best || (v == best && i2 < bi)) { best = v; bi = i2; }
    }
    ostar[ij] = bi;
  }
}

// ---------------- generic bf16 GEMM:  C[m,n] = sum_k A[m,k] * BT[n,k] ----------------

__device__ __forceinline__ void stage_bf16(const __hip_bfloat16* __restrict__ src,
                                           __hip_bfloat16* dst,
                                           int r0, int k0, int ld, int tid) {
  const int srow = tid >> 1;
  const int scol = (tid & 1) << 4;
  const __hip_bfloat16* g = src + (size_t)(r0 + srow) * ld + k0 + scol;
  uint4 v0 = *(const uint4*)(g);
  uint4 v1 = *(const uint4*)(g + 8);
  *(uint4*)(dst + srow * 32 + scol) = v0;
  *(uint4*)(dst + srow * 32 + scol + 8) = v1;
}

template<int EPI>
__global__ __launch_bounds__(256) void k_gemm(
    const __hip_bfloat16* __restrict__ Ap, const __hip_bfloat16* __restrict__ Bp,
    float* __restrict__ Cf, __hip_bfloat16* __restrict__ Cb,
    const float* __restrict__ bias, const float* __restrict__ mskf,
    int M, int N, int lda, int ldb, int ldc, int Npad,
    int ktPerSlice, int KT)
{
  __shared__ __attribute__((aligned(16))) __hip_bfloat16 As[128 * 32];
  __shared__ __attribute__((aligned(16))) __hip_bfloat16 Bs[128 * 32];
  const int tid = threadIdx.x;
  const int lane = tid & 63;
  const int wave = tid >> 6;
  const int wm = wave >> 1, wn = wave & 1;
  const int m0 = blockIdx.y * 128, n0 = blockIdx.x * 128;
  int kt0 = blockIdx.z * ktPerSlice;
  int kt1 = kt0 + ktPerSlice; if (kt1 > KT) kt1 = KT;

  f32x4 acc[4][4];
  f32x4 zero = {0.f, 0.f, 0.f, 0.f};
#pragma unroll
  for (int i = 0; i < 4; ++i)
#pragma unroll
    for (int j = 0; j < 4; ++j) acc[i][j] = zero;

  for (int kt = kt0; kt < kt1; ++kt) {
    const int k0 = kt * 32;
    stage_bf16(Ap, As, m0, k0, lda, tid);
    stage_bf16(Bp, Bs, n0, k0, ldb, tid);
    __syncthreads();
    bf16x8 af[4], bfv[4];
#pragma unroll
    for (int mi = 0; mi < 4; ++mi)
      af[mi] = *(const bf16x8*)(As + (wm * 64 + mi * 16 + (lane & 15)) * 32 + (lane >> 4) * 8);
#pragma unroll
    for (int ni = 0; ni < 4; ++ni)
      bfv[ni] = *(const bf16x8*)(Bs + (wn * 64 + ni * 16 + (lane & 15)) * 32 + (lane >> 4) * 8);
#pragma unroll
    for (int mi = 0; mi < 4; ++mi)
#pragma unroll
      for (int ni = 0; ni < 4; ++ni)
        acc[mi][ni] = __builtin_amdgcn_mfma_f32_16x16x32_bf16(af[mi], bfv[ni], acc[mi][ni], 0, 0, 0);
    __syncthreads();
  }

  const int rb = (lane >> 4) * 4;
  const int cb = lane & 15;
#pragma unroll
  for (int mi = 0; mi < 4; ++mi) {
#pragma unroll
    for (int ni = 0; ni < 4; ++ni) {
      const int col = n0 + wn * 64 + ni * 16 + cb;
#pragma unroll
      for (int r = 0; r < 4; ++r) {
        const int row = m0 + wm * 64 + mi * 16 + rb + r;
        const float v = acc[mi][ni][r];
        if (EPI == EPI_F32) {
          if (row < M && col < N) Cf[(size_t)row * ldc + col] = v;
        } else if (EPI == EPI_ATOM) {
          if (row < M && col < N) atomicAdd(Cf + (size_t)row * ldc + col, v);
        } else if (EPI == EPI_BKG) {
          if (row < M && col < Npad) {
            float ov = 0.f;
            if (col < N) ov = (v + bias[col]) * (1.f - mskf[(size_t)(row & 255) * ldc + col]);
            Cb[(size_t)row * ldc + col] = __float2bfloat16(ov);
          }
        } else { // EPI_AUX
          if (row < M && col < N) Cb[(size_t)row * ldc + col] = __float2bfloat16(v + bias[row]);
        }
      }
    }
  }
}

// ---------------- specialized GEMM B: msk = mP[256][K2] x w2[O][K2]^T ----------------
// BM=256 (entire M), BN=64, split-K; w2 stays f32 and is fetched exactly once.

__global__ __launch_bounds__(256) void k_gemm_msk(
    const __hip_bfloat16* __restrict__ A,  // mP [256][K2P_]
    const float* __restrict__ B,           // w2 [O_][K2_] f32
    float* __restrict__ C,                 // mskF [256][OP_] (pre-zeroed, atomic)
    int ktPerSlice)
{
  __shared__ __attribute__((aligned(16))) __hip_bfloat16 As[256 * 32];
  __shared__ __attribute__((aligned(16))) __hip_bfloat16 Bs[64 * 32];
  const int tid = threadIdx.x;
  const int lane = tid & 63;
  const int wave = tid >> 6;
  const int n0 = blockIdx.x * 64;
  int kt0 = blockIdx.z * ktPerSlice;
  int kt1 = kt0 + ktPerSlice; if (kt1 > 745) kt1 = 745;

  const int brow = tid >> 2;           // 0..63  B-tile row
  const int bcol = (tid & 3) << 3;     // 0,8,16,24
  const int grow = n0 + brow;
  const bool rok = grow < O_;
  const float* gB = B + (size_t)grow * K2_ + bcol;

  f32x4 acc[4][4];
  f32x4 zero = {0.f, 0.f, 0.f, 0.f};
#pragma unroll
  for (int i = 0; i < 4; ++i)
#pragma unroll
    for (int j = 0; j < 4; ++j) acc[i][j] = zero;

  for (int kt = kt0; kt < kt1; ++kt) {
    const int k0 = kt * 32;
    // stage A: 1 row per thread, 32 cols = 4x uint4
    {
      const __hip_bfloat16* g = A + (size_t)tid * K2P_ + k0;
      uint4 v0 = *(const uint4*)(g);
      uint4 v1 = *(const uint4*)(g + 8);
      uint4 v2 = *(const uint4*)(g + 16);
      uint4 v3 = *(const uint4*)(g + 24);
      __hip_bfloat16* d = As + tid * 32;
      *(uint4*)(d) = v0; *(uint4*)(d + 8) = v1;
      *(uint4*)(d + 16) = v2; *(uint4*)(d + 24) = v3;
    }
    // stage B: 64 rows x 32 f32 cols; 4 threads/row, 8 cols each via float2
    {
      alignas(16) __hip_bfloat16 tmp[8];
      if (rok && (k0 + 32) <= K2_) {
        const float* g = gB + k0;
        float2 p0 = *(const float2*)(g);
        float2 p1 = *(const float2*)(g + 2);
        float2 p2 = *(const float2*)(g + 4);
        float2 p3 = *(const float2*)(g + 6);
        tmp[0] = __float2bfloat16(p0.x); tmp[1] = __float2bfloat16(p0.y);
        tmp[2] = __float2bfloat16(p1.x); tmp[3] = __float2bfloat16(p1.y);
        tmp[4] = __float2bfloat16(p2.x); tmp[5] = __float2bfloat16(p2.y);
        tmp[6] = __float2bfloat16(p3.x); tmp[7] = __float2bfloat16(p3.y);
      } else {
        const float* g = gB + k0;
#pragma unroll
        for (int c = 0; c < 8; ++c) {
          float v = (rok && (k0 + bcol + c) < K2_) ? g[c] : 0.f;
          tmp[c] = __float2bfloat16(v);
        }
      }
      *(uint4*)(Bs + brow * 32 + bcol) = *(const uint4*)(tmp);
    }
    __syncthreads();
    bf16x8 af[4], bfv[4];
#pragma unroll
    for (int mi = 0; mi < 4; ++mi)
      af[mi] = *(const bf16x8*)(As + (wave * 64 + mi * 16 + (lane & 15)) * 32 + (lane >> 4) * 8);
#pragma unroll
    for (int ni = 0; ni < 4; ++ni)
      bfv[ni] = *(const bf16x8*)(Bs + (ni * 16 + (lane & 15)) * 32 + (lane >> 4) * 8);
#pragma unroll
    for (int mi = 0; mi < 4; ++mi)
#pragma unroll
      for (int ni = 0; ni < 4; ++ni)
        acc[mi][ni] = __builtin_amdgcn_mfma_f32_16x16x32_bf16(af[mi], bfv[ni], acc[mi][ni], 0, 0, 0);
    __syncthreads();
  }

  const int rb = (lane >> 4) * 4;
  const int cb = lane & 15;
#pragma unroll
  for (int mi = 0; mi < 4; ++mi) {
#pragma unroll
    for (int ni = 0; ni < 4; ++ni) {
      const int col = n0 + ni * 16 + cb;
      if (col < O_) {
#pragma unroll
        for (int r = 0; r < 4; ++r) {
          const int row = wave * 64 + mi * 16 + rb + r;
          atomicAdd(C + (size_t)row * OP_ + col, acc[mi][ni][r]);
        }
      }
    }
  }
}

// mskF raw sums -> + bias, rewrite f32 and bf16 (pad cols -> 0)
__global__ __launch_bounds__(256) void k_msk_fin(float* __restrict__ mskF,
                                                 __hip_bfloat16* __restrict__ mskB,
                                                 const float* __restrict__ b2) {
  int idx = blockIdx.x * 256 + threadIdx.x;
  if (idx >= NM_ * OP_) return;
  int n = idx % OP_;
  float v = 0.f;
  if (n < O_) v = mskF[idx] + b2[n];
  mskF[idx] = v;
  mskB[idx] = __float2bfloat16(v);
}

// ---------------- patch overlap-add / epilogue kernels ----------------

__device__ __forceinline__ int cntv(int t) { return (t >= 8 && t < 504) ? 2 : 1; }

__global__ __launch_bounds__(256) void k_out_asm(const float* __restrict__ P, float* __restrict__ out) {
  int idx = blockIdx.x * 256 + threadIdx.x;
  if (idx >= 3 * S_ * S_) return;
  int x = idx % S_;
  int t = idx / S_;
  int y = t % S_;
  int d = t / S_;
  int Y = y + 4, X = x + 4;
  int iy0 = (Y - 8) >> 3; if (iy0 < 0) iy0 = 0;
  int iy1 = Y >> 3; if (iy1 > 62) iy1 = 62;
  int jx0 = (X - 8) >> 3; if (jx0 < 0) jx0 = 0;
  int jx1 = X >> 3; if (jx1 > 62) jx1 = 62;
  float s = 0.f;
  for (int i = iy0; i <= iy1; ++i)
    for (int j = jx0; j <= jx1; ++j)
      s += P[(size_t)(i * 63 + j) * NB_ + d * 256 + (Y - 8 * i) * 16 + (X - 8 * j)];
  out[idx] = s;
}

__global__ __launch_bounds__(256) void k_mr512(const float* __restrict__ P, float* __restrict__ mr) {
  int idx = blockIdx.x * 256 + threadIdx.x;
  if (idx >= 512 * 512) return;
  int x = idx & 511, y = idx >> 9;
  int iy0 = (y - 8) >> 3; if (iy0 < 0) iy0 = 0;
  int iy1 = y >> 3; if (iy1 > 62) iy1 = 62;
  int jx0 = (x - 8) >> 3; if (jx0 < 0) jx0 = 0;
  int jx1 = x >> 3; if (jx1 > 62) jx1 = 62;
  float s = 0.f;
  for (int i = iy0; i <= iy1; ++i)
    for (int j = jx0; j <= jx1; ++j)
      s += P[(size_t)(i * 63 + j) * NM_ + (y - 8 * i) * 16 + (x - 8 * j)];
  mr[idx] = s;
}

__global__ __launch_bounds__(256) void k_hole(const float* __restrict__ mr,
                                              const float* __restrict__ up2w, const float* __restrict__ up2b,
                                              const float* __restrict__ up3w, const float* __restrict__ up3b,
                                              float* __restrict__ out) {
  int idx = blockIdx.x * 256 + threadIdx.x;
  if (idx >= 6 * 1016 * 1016) return;
  int X = idx % 1016;
  int t = idx / 1016;
  int Y = t % 1016;
  int c = t / 1016;
  int Yp = Y + 4, Xp = X + 4;
  int ys = Yp >> 1, xs = Xp >> 1;
  int ky = Yp & 1, kx = Xp & 1;
  float mv = mr[ys * 512 + xs] * up2w[(c << 2) | (ky << 1) | kx] + up2b[c];
  float wmv = (float)(cntv(ys) * cntv(xs)) * up3w[(ky << 1) | kx] + up3b[0];
  out[idx] = mv / wmv;
}

__global__ __launch_bounds__(256) void k_raw(const __hip_bfloat16* __restrict__ aux,
                                             const int* __restrict__ ostar,
                                             float* __restrict__ out) {
  int idx = blockIdx.x * 256 + threadIdx.x;
  if (idx >= 18 * S_ * S_) return;
  int x = idx % S_;
  int t = idx / S_;
  int y = t % S_;
  int d = t / S_;
  int Y = y + 4, X = x + 4;
  int iy0 = (Y - 8) >> 3; if (iy0 < 0) iy0 = 0;
  int iy1 = Y >> 3; if (iy1 > 62) iy1 = 62;
  int jx0 = (X - 8) >> 3; if (jx0 < 0) jx0 = 0;
  int jx1 = X >> 3; if (jx1 > 62) jx1 = 62;
  float s = 0.f;
  for (int i = iy0; i <= iy1; ++i)
    for (int j = jx0; j <= jx1; ++j) {
      int o = ostar[i * 63 + j];
      s += __bfloat162float(aux[(size_t)o * NA_ + d * 256 + (Y - 8 * i) * 16 + (X - 8 * j)]);
    }
  s /= (float)(cntv(Y) * cntv(X));
  out[idx] = s;
}

// ---------------- launch ----------------

extern "C" void kernel_launch(void* const* d_in, const int* in_sizes, int n_in,
                              void* d_out, int out_size, void* d_ws, size_t ws_size,
                              hipStream_t stream) {
  const float* cos_  = (const float*)d_in[0];
  const float* bimg  = (const float*)d_in[1];
  const float* mask  = (const float*)d_in[2];
  const float* auxr  = (const float*)d_in[3];
  const float* w1    = (const float*)d_in[4];
  const float* b1    = (const float*)d_in[5];
  const float* w2    = (const float*)d_in[6];
  const float* b2    = (const float*)d_in[7];
  const float* waux  = (const float*)d_in[8];
  const float* baux  = (const float*)d_in[9];
  const float* up2w  = (const float*)d_in[10];
  const float* up2b  = (const float*)d_in[11];
  const float* up3w  = (const float*)d_in[12];
  const float* up3b  = (const float*)d_in[13];
  (void)in_sizes; (void)n_in; (void)out_size; (void)ws_size;

  char* ws = (char*)d_ws;
  size_t off = 0;
  auto take = [&](size_t bytes) { char* p = ws + off; off += (bytes + 255) & ~(size_t)255; return p; };
  __hip_bfloat16* cosT  = (__hip_bfloat16*)take((size_t)4096 * OP_ * 2);   // [4096][OP_]
  __hip_bfloat16* bP    = (__hip_bfloat16*)take((size_t)NB_ * LP_ * 2);    // [768][4000]
  __hip_bfloat16* mP    = (__hip_bfloat16*)take((size_t)NM_ * K2P_ * 2);   // [256][23840]
  __hip_bfloat16* aP    = (__hip_bfloat16*)take((size_t)NA_ * LP_ * 2);    // [4608][4000]
  __hip_bfloat16* wXb   = (__hip_bfloat16*)take((size_t)5888 * LP_ * 2);   // waux bf16, M-padded
  float*          mskF  = (float*)take((size_t)NM_ * OP_ * 4);             // [256][OP_] f32
  __hip_bfloat16* mskB  = (__hip_bfloat16*)take((size_t)NM_ * OP_ * 2);
  __hip_bfloat16* bkgB  = (__hip_bfloat16*)take((size_t)NB_ * OP_ * 2);
  __hip_bfloat16* auxB  = (__hip_bfloat16*)take((size_t)O_ * NA_ * 2);     // [5766][4608]
  float*          Pout  = (float*)take((size_t)L_ * NB_ * 4);
  float*          Pmsk  = (float*)take((size_t)L_ * NM_ * 4);
  int*            ostar = (int*)take((size_t)L_ * 4);
  float*          mr    = (float*)take((size_t)512 * 512 * 4);

  // w1b (bf16, [5888][LP_], 47.1 MB) aliases auxB (53.1 MB): dead before GEMM C writes auxB
  __hip_bfloat16* w1b = auxB;

  float* outMain = (float*)d_out;            // [3][504][504]
  float* outHole = outMain + 762048;         // [6][1016][1016]
  float* outRaw  = outMain + 6955584;        // [18][504][504]

  // materialize bf16 operands
  k_cos_transpose<<<dim3(91, 63), 256, 0, stream>>>(cos_, cosT);
  k_patch<<<(NB_ * LP_ + 255) / 256, 256, 0, stream>>>(bimg, bP, 3);
  k_patch<<<(NA_ * LP_ + 255) / 256, 256, 0, stream>>>(auxr, aP, 18);
  k_patch_m<<<(NM_ * K2P_ + 255) / 256, 256, 0, stream>>>(mask, mP);
  k_cvt_pad<<<(O_ * LP_ + 255) / 256, 256, 0, stream>>>(waux, wXb, O_, L_, LP_);
  k_cvt_pad<<<(O_ * LP_ + 255) / 256, 256, 0, stream>>>(w1, w1b, O_, L_, LP_);
  k_argmax<<<63, 256, 0, stream>>>(cos_, ostar);

  // GEMM B: mskT[hw][o]  (BM=256 covers all M, w2 f32 fetched once; split-K=8, atomic)
  hipMemsetAsync(mskF, 0, (size_t)NM_ * OP_ * 4, stream);
  k_gemm_msk<<<dim3(91, 1, 8), 256, 0, stream>>>(mP, w2, mskF, 94);
  k_msk_fin<<<(NM_ * OP_ + 255) / 256, 256, 0, stream>>>(mskF, mskB, b2);

  // GEMM A: bkgT[dhw][o] = (sum + b1) * (1 - msk)   (all-bf16 now)
  k_gemm<EPI_BKG><<<dim3(46, 6, 1), 256, 0, stream>>>(
      bP, w1b, nullptr, bkgB, b1, mskF,
      NB_, O_, LP_, LP_, OP_, OP_, 125, 125);

  // GEMM C: aux[o][dhw] = sum + baux[o]   (overwrites w1b region - w1b is dead)
  k_gemm<EPI_AUX><<<dim3(36, 46, 1), 256, 0, stream>>>(
      wXb, aP, nullptr, auxB, baux, nullptr,
      O_, NA_, LP_, LP_, NA_, NA_, 125, 125);

  // GEMM D: P_out[ij][dhw]
  k_gemm<EPI_F32><<<dim3(6, 32, 1), 256, 0, stream>>>(
      cosT, bkgB, Pout, nullptr, nullptr, nullptr,
      L_, NB_, OP_, OP_, NB_, NB_, 181, 181);

  // GEMM E: P_msk[ij][hw]  (split-K=4, atomic)
  hipMemsetAsync(Pmsk, 0, (size_t)L_ * NM_ * 4, stream);
  k_gemm<EPI_ATOM><<<dim3(2, 32, 4), 256, 0, stream>>>(
      cosT, mskB, Pmsk, nullptr, nullptr, nullptr,
      L_, NM_, OP_, OP_, NM_, NM_, 46, 181);

  // assemble outputs
  k_out_asm<<<(3 * S_ * S_ + 255) / 256, 256, 0, stream>>>(Pout, outMain);
  k_mr512<<<(512 * 512) / 256, 256, 0, stream>>>(Pmsk, mr);
  k_hole<<<(6 * 1016 * 1016 + 255) / 256, 256, 0, stream>>>(mr, up2w, up2b, up3w, up3b, outHole);
  k_raw<<<(18 * S_ * S_ + 255) / 256, 256, 0, stream>>>(auxB, ostar, outRaw);
}